// Round 6
// baseline (248.949 us; speedup 1.0000x reference)
//
#include <hip/hip_runtime.h>
#include <hip/hip_cooperative_groups.h>
#include <math.h>

namespace cg = cooperative_groups;

static constexpr int NN   = 4096;
static constexpr int INC  = 256;
static constexpr int OUTC = 64;

typedef _Float16 half8 __attribute__((ext_vector_type(8)));
typedef float floatx4 __attribute__((ext_vector_type(4)));

__device__ __forceinline__ float lrelu(float x) {
    return fmaxf(x, 0.f) + 0.2f * fminf(x, 0.f);
}
__device__ __forceinline__ float elu1(float x) {
    return x > 0.f ? x : (__expf(x) - 1.f);
}

// Single cooperative kernel. 256 blocks x 1024 threads (16 waves), 1 block/CU.
// Phase 1 (per block, rows i0..i0+15):
//   - wave w dense-streams adj row i0+w (16 KB) -> 64-bit/lane bitmask in LDS
//   - wave w computes Wh row i0+w (H via wave-uniform scalar loads, W from L2),
//     writes fp16 WhT (global), f2 (global), f1 (LDS)
// grid.sync()
// Phase 2: verified MFMA attention loop; mask bytes from LDS (pad 520B -> 16
//   distinct banks, 4-lane broadcast), f1 from LDS, WhT from L2, exact softmax
//   max via monotone lrelu + global max(f2).
__global__ __launch_bounds__(1024, 4) void k_gat(const int* __restrict__ adj,
                                                 const float* __restrict__ H,
                                                 const float* __restrict__ W,
                                                 const float* __restrict__ a,
                                                 unsigned short* __restrict__ WhT,
                                                 float* __restrict__ f2g,
                                                 float* __restrict__ out) {
    __shared__ __align__(16) float sf2[NN];                 // 16 KB
    __shared__ __align__(16) float sacc[16 * 1024];         // 64 KB (phase1: Tl alias)
    __shared__ __align__(8) unsigned long long smask[16 * 65]; // 8.32 KB, row stride 65
    __shared__ float sden[16 * 16];
    __shared__ float smax[16];
    __shared__ float sf1[16];

    const int t = threadIdx.x;
    const int w = t >> 6;          // wave 0..15
    const int l = t & 63;
    const int i0 = blockIdx.x * 16;
    const int row = i0 + w;

    // ---------------- phase 1a: adj row -> LDS bitmask ----------------
    {
        // lane l covers j in [l*64, l*64+64): 16x int4, 256B contiguous per lane
        const int4* ap = (const int4*)(adj + (size_t)row * NN) + l * 16;
        unsigned long long bits = 0ull;
        #pragma unroll 4
        for (int k = 0; k < 16; ++k) {
            const int4 v = ap[k];
            const unsigned long long nib =
                  (unsigned long long)(v.x > 0)
                | ((unsigned long long)(v.y > 0) << 1)
                | ((unsigned long long)(v.z > 0) << 2)
                | ((unsigned long long)(v.w > 0) << 3);
            bits |= nib << (4 * k);
        }
        smask[w * 65 + l] = bits;
    }

    // ---------------- phase 1b: Wh row, f1/f2, WhT ----------------
    {
        _Float16* Tl = (_Float16*)sacc;                    // 16 x 68 halves, aliased
        const int c = l;                                   // channel
        const float4* Hr = (const float4*)(H + (size_t)row * INC);  // wave-uniform
        float acc = 0.f;
        #pragma unroll 8
        for (int k4 = 0; k4 < INC / 4; ++k4) {
            const float4 h = Hr[k4];
            acc = fmaf(h.x, W[(k4 * 4 + 0) * OUTC + c],
                  fmaf(h.y, W[(k4 * 4 + 1) * OUTC + c],
                  fmaf(h.z, W[(k4 * 4 + 2) * OUTC + c],
                  fmaf(h.w, W[(k4 * 4 + 3) * OUTC + c], acc))));
        }
        Tl[w * 68 + c] = (_Float16)acc;
        float v1 = acc * a[c];
        float v2 = acc * a[OUTC + c];
        #pragma unroll
        for (int off = 32; off; off >>= 1) {
            v1 += __shfl_xor(v1, off);
            v2 += __shfl_xor(v2, off);
        }
        if (c == 0) { sf1[w] = v1; f2g[row] = v2; }
        __syncthreads();
        if (t < 256) {
            const int c2 = t >> 2;
            const int rs = (t & 3) * 4;
            ushort4 u;
            u.x = *(const unsigned short*)&Tl[(rs + 0) * 68 + c2];
            u.y = *(const unsigned short*)&Tl[(rs + 1) * 68 + c2];
            u.z = *(const unsigned short*)&Tl[(rs + 2) * 68 + c2];
            u.w = *(const unsigned short*)&Tl[(rs + 3) * 68 + c2];
            *(ushort4*)(WhT + (size_t)c2 * NN + i0 + rs) = u;
        }
    }
    __threadfence();               // device-scope: publish WhT/f2g before grid sync
    cg::this_grid().sync();

    // ---------------- phase 2: attention ----------------
    const int m = l & 15;          // A row (= output row within tile)
    const int quad = l >> 4;       // k-group

    // f2 -> LDS + global max
    {
        const float4 v = ((const float4*)f2g)[t];
        ((float4*)sf2)[t] = v;
        float mloc = fmaxf(fmaxf(v.x, v.y), fmaxf(v.z, v.w));
        #pragma unroll
        for (int off = 32; off; off >>= 1) mloc = fmaxf(mloc, __shfl_xor(mloc, off));
        if (l == 0) smax[w] = mloc;
    }
    __syncthreads();
    float maxf2 = smax[0];
    #pragma unroll
    for (int k = 1; k < 16; ++k) maxf2 = fmaxf(maxf2, smax[k]);

    const float f1r = sf1[m];
    const float mrow = lrelu(f1r + maxf2);  // exact per-row softmax max (lrelu monotone)
    float den = 0.f;
    floatx4 acc[4] = {{0.f,0.f,0.f,0.f},{0.f,0.f,0.f,0.f},{0.f,0.f,0.f,0.f},{0.f,0.f,0.f,0.f}};
    const int jbase = w * 32 + quad * 8;
    // mask byte for (row m, jbase + it*512): byte index w*4+quad + it*64, row stride 520
    const unsigned char* mrow_p = (const unsigned char*)smask + m * 520 + w * 4 + quad;

    #pragma unroll 2
    for (int it = 0; it < 8; ++it) {
        const int j = jbase + it * 512;
        const unsigned int mb = mrow_p[it * 64];
        const float4 g0 = *(const float4*)(sf2 + j);
        const float4 g1 = *(const float4*)(sf2 + j + 4);
        half8 af;
        {
            float p;
            p = __expf(lrelu(f1r + g0.x) - mrow); den += p; af[0] = (mb & 1u)   ? (_Float16)p : (_Float16)0.f;
            p = __expf(lrelu(f1r + g0.y) - mrow); den += p; af[1] = (mb & 2u)   ? (_Float16)p : (_Float16)0.f;
            p = __expf(lrelu(f1r + g0.z) - mrow); den += p; af[2] = (mb & 4u)   ? (_Float16)p : (_Float16)0.f;
            p = __expf(lrelu(f1r + g0.w) - mrow); den += p; af[3] = (mb & 8u)   ? (_Float16)p : (_Float16)0.f;
            p = __expf(lrelu(f1r + g1.x) - mrow); den += p; af[4] = (mb & 16u)  ? (_Float16)p : (_Float16)0.f;
            p = __expf(lrelu(f1r + g1.y) - mrow); den += p; af[5] = (mb & 32u)  ? (_Float16)p : (_Float16)0.f;
            p = __expf(lrelu(f1r + g1.z) - mrow); den += p; af[6] = (mb & 64u)  ? (_Float16)p : (_Float16)0.f;
            p = __expf(lrelu(f1r + g1.w) - mrow); den += p; af[7] = (mb & 128u) ? (_Float16)p : (_Float16)0.f;
        }
        #pragma unroll
        for (int nt = 0; nt < 4; ++nt) {
            const half8 bf = *(const half8*)(WhT + (size_t)(nt * 16 + m) * NN + j);
            acc[nt] = __builtin_amdgcn_mfma_f32_16x16x32_f16(af, bf, acc[nt], 0, 0, 0);
        }
    }
    den += __shfl_xor(den, 16);
    den += __shfl_xor(den, 32);
    if (l < 16) sden[w * 16 + l] = den;
    // D layout (verified R2): out row = quad*4 + reg, channel = nt*16 + (lane&15)
    #pragma unroll
    for (int nt = 0; nt < 4; ++nt)
        #pragma unroll
        for (int r = 0; r < 4; ++r)
            sacc[w * 1024 + (quad * 4 + r) * 64 + nt * 16 + m] = acc[nt][r];
    __syncthreads();
    float s = 0.f;
    #pragma unroll
    for (int w2 = 0; w2 < 16; ++w2) s += sacc[w2 * 1024 + t];
    float dden = 0.f;
    const int orow = t >> 6;
    #pragma unroll
    for (int w2 = 0; w2 < 16; ++w2) dden += sden[w2 * 16 + orow];
    out[(size_t)i0 * OUTC + t] = elu1(s / dden);
}

extern "C" void kernel_launch(void* const* d_in, const int* in_sizes, int n_in,
                              void* d_out, int out_size, void* d_ws, size_t ws_size,
                              hipStream_t stream) {
    const float* H  = (const float*)d_in[0];
    const int* adj  = (const int*)d_in[1];
    const float* W  = (const float*)d_in[2];
    const float* a  = (const float*)d_in[3];
    float* out = (float*)d_out;
    char* ws = (char*)d_ws;
    // ws: WhT 512K | f2 16K
    unsigned short* WhT = (unsigned short*)(ws);
    float* f2g = (float*)(ws + (512 << 10));

    void* args[] = { (void*)&adj, (void*)&H, (void*)&W, (void*)&a,
                     (void*)&WhT, (void*)&f2g, (void*)&out };
    hipLaunchCooperativeKernel((void*)k_gat, dim3(256), dim3(1024), args, 0, stream);
}

// Round 7
// 127.528 us; speedup vs baseline: 1.9521x; 1.9521x over previous
//
#include <hip/hip_runtime.h>
#include <math.h>

static constexpr int NN   = 4096;
static constexpr int INC  = 256;
static constexpr int OUTC = 64;

typedef _Float16 half8 __attribute__((ext_vector_type(8)));
typedef float floatx4 __attribute__((ext_vector_type(4)));

__device__ __forceinline__ float lrelu(float x) {
    return fmaxf(x, 0.f) + 0.2f * fminf(x, 0.f);
}
__device__ __forceinline__ float elu1(float x) {
    return x > 0.f ? x : (__expf(x) - 1.f);
}

// K1: Wh = H@W -> fp16 WhT (transposed 64 x 4096); f1 = Wh@a1; f2 = Wh@a2.
// 16 rows/block, 256 blocks, small LDS (R5-verified wh branch, standalone).
__global__ __launch_bounds__(256) void k_wh(const float* __restrict__ H,
                                            const float* __restrict__ W,
                                            const float* __restrict__ a,
                                            unsigned short* __restrict__ WhT,
                                            float* __restrict__ f1,
                                            float* __restrict__ f2) {
    __shared__ __align__(16) float Hl[16 * INC];   // 16 KB
    __shared__ _Float16 Tl[16 * 68];               // 2.2 KB transpose buffer
    const int t = threadIdx.x;
    const int i0 = blockIdx.x * 16;
    {
        const float4* H4 = (const float4*)(H + i0 * INC);
        float4* Hl4 = (float4*)Hl;
        #pragma unroll
        for (int u = 0; u < 4; ++u) Hl4[u * 256 + t] = H4[u * 256 + t];
    }
    __syncthreads();
    const int c = t & 63;       // channel (lane)
    const int g = t >> 6;       // wave -> row group
    const float a1c = a[c];
    const float a2c = a[OUTC + c];
    float acc[4] = {0.f, 0.f, 0.f, 0.f};
    const float4* Hl4 = (const float4*)Hl;
    #pragma unroll 4
    for (int k4 = 0; k4 < INC / 4; ++k4) {
        const float w0 = W[(k4 * 4 + 0) * OUTC + c];   // coalesced, L2-hit
        const float w1 = W[(k4 * 4 + 1) * OUTC + c];
        const float w2 = W[(k4 * 4 + 2) * OUTC + c];
        const float w3 = W[(k4 * 4 + 3) * OUTC + c];
        #pragma unroll
        for (int s = 0; s < 4; ++s) {
            const float4 h = Hl4[(g + 4 * s) * (INC / 4) + k4];
            acc[s] = fmaf(h.x, w0, fmaf(h.y, w1, fmaf(h.z, w2, fmaf(h.w, w3, acc[s]))));
        }
    }
    #pragma unroll
    for (int s = 0; s < 4; ++s) {
        const int r = g + 4 * s;
        Tl[r * 68 + c] = (_Float16)acc[s];
        float v1 = acc[s] * a1c;
        float v2 = acc[s] * a2c;
        #pragma unroll
        for (int off = 32; off; off >>= 1) {
            v1 += __shfl_xor(v1, off);
            v2 += __shfl_xor(v2, off);
        }
        if (c == 0) { f1[i0 + r] = v1; f2[i0 + r] = v2; }
    }
    __syncthreads();
    const int c2 = t >> 2;
    const int rs = (t & 3) * 4;
    ushort4 u;
    u.x = *(const unsigned short*)&Tl[(rs + 0) * 68 + c2];
    u.y = *(const unsigned short*)&Tl[(rs + 1) * 68 + c2];
    u.z = *(const unsigned short*)&Tl[(rs + 2) * 68 + c2];
    u.w = *(const unsigned short*)&Tl[(rs + 3) * 68 + c2];
    *(ushort4*)(WhT + c2 * NN + i0 + rs) = u;
}

// K2: fused attention with in-kernel adj->bitmask, software-pipelined.
// 256 blocks x 1024 threads (16 waves); block owns 16 rows x all 4096 j,
// processed in 8 tiles of 512 j. Wave w streams adj row i0+w: per tile,
// 8 coalesced dword loads (lane i -> j = tile*512 + e*64 + i), __ballot
// packs 64 j-bits per round into a double-buffered LDS mask. Loads for
// tile t+1 issue before compute of tile t (adj HBM stream hides behind
// exp + MFMA). No device-scope fences, no grid sync.
__global__ __launch_bounds__(1024, 4) void k_att(const int* __restrict__ adj,
                                                 const _Float16* __restrict__ WhT,
                                                 const float* __restrict__ f1,
                                                 const float* __restrict__ f2,
                                                 float* __restrict__ out) {
    __shared__ __align__(16) float sf2[NN];                   // 16 KB
    __shared__ __align__(16) float sacc[16 * 1024];           // 64 KB
    __shared__ __align__(8) unsigned long long smask[2][16][9]; // 2.3 KB (pad 9)
    __shared__ float sden[16 * 16];
    __shared__ float smax[16];
    const int t = threadIdx.x;
    const int w = t >> 6;          // wave 0..15
    const int l = t & 63;
    const int m = l & 15;          // A row (= output row within tile)
    const int quad = l >> 4;       // k-group
    const int i0 = blockIdx.x * 16;

    // f2 -> LDS + block-wide max (exact softmax max via monotone lrelu)
    {
        const float4 v = ((const float4*)f2)[t];
        ((float4*)sf2)[t] = v;
        float mloc = fmaxf(fmaxf(v.x, v.y), fmaxf(v.z, v.w));
        #pragma unroll
        for (int off = 32; off; off >>= 1) mloc = fmaxf(mloc, __shfl_xor(mloc, off));
        if (l == 0) smax[w] = mloc;
    }

    // prologue: masks for tile 0 (wave w owns adj row i0+w)
    const int* arow = adj + (size_t)(i0 + w) * NN;
    int pv[8];
    #pragma unroll
    for (int e = 0; e < 8; ++e) pv[e] = arow[e * 64 + l];
    #pragma unroll
    for (int e = 0; e < 8; ++e) {
        const unsigned long long bm = __ballot(pv[e] > 0);
        if (l == 0) smask[0][w][e] = bm;
    }
    __syncthreads();

    float maxf2 = smax[0];
    #pragma unroll
    for (int k = 1; k < 16; ++k) maxf2 = fmaxf(maxf2, smax[k]);
    const float f1r = f1[i0 + m];
    const float mrow = lrelu(f1r + maxf2);

    float den = 0.f;
    floatx4 acc[4] = {{0.f,0.f,0.f,0.f},{0.f,0.f,0.f,0.f},{0.f,0.f,0.f,0.f},{0.f,0.f,0.f,0.f}};
    const int jb = w * 32 + quad * 8;          // j-offset within tile
    // mask byte for (row m, this lane's j-range): u64 e = w>>1, byte (w&1)*4+quad
    const unsigned char* mbase = (const unsigned char*)&smask[0][0][0]
                               + m * 72 + (w >> 1) * 8 + (w & 1) * 4 + quad;

    for (int tt = 0; tt < 8; ++tt) {
        if (tt < 7) {   // issue next tile's adj loads early (hide HBM latency)
            #pragma unroll
            for (int e = 0; e < 8; ++e) pv[e] = arow[(tt + 1) * 512 + e * 64 + l];
        }
        const int j = tt * 512 + jb;
        const unsigned int mb = mbase[(tt & 1) * (16 * 72)];
        const float4 g0 = *(const float4*)(sf2 + j);
        const float4 g1 = *(const float4*)(sf2 + j + 4);
        half8 af;
        {
            float p;
            p = __expf(lrelu(f1r + g0.x) - mrow); den += p; af[0] = (mb & 1u)   ? (_Float16)p : (_Float16)0.f;
            p = __expf(lrelu(f1r + g0.y) - mrow); den += p; af[1] = (mb & 2u)   ? (_Float16)p : (_Float16)0.f;
            p = __expf(lrelu(f1r + g0.z) - mrow); den += p; af[2] = (mb & 4u)   ? (_Float16)p : (_Float16)0.f;
            p = __expf(lrelu(f1r + g0.w) - mrow); den += p; af[3] = (mb & 8u)   ? (_Float16)p : (_Float16)0.f;
            p = __expf(lrelu(f1r + g1.x) - mrow); den += p; af[4] = (mb & 16u)  ? (_Float16)p : (_Float16)0.f;
            p = __expf(lrelu(f1r + g1.y) - mrow); den += p; af[5] = (mb & 32u)  ? (_Float16)p : (_Float16)0.f;
            p = __expf(lrelu(f1r + g1.z) - mrow); den += p; af[6] = (mb & 64u)  ? (_Float16)p : (_Float16)0.f;
            p = __expf(lrelu(f1r + g1.w) - mrow); den += p; af[7] = (mb & 128u) ? (_Float16)p : (_Float16)0.f;
        }
        #pragma unroll
        for (int nt = 0; nt < 4; ++nt) {
            const half8 bf = *(const half8*)(WhT + (size_t)(nt * 16 + m) * NN + j);
            acc[nt] = __builtin_amdgcn_mfma_f32_16x16x32_f16(af, bf, acc[nt], 0, 0, 0);
        }
        if (tt < 7) {   // pack next tile's masks into the other buffer
            #pragma unroll
            for (int e = 0; e < 8; ++e) {
                const unsigned long long bm = __ballot(pv[e] > 0);
                if (l == 0) smask[(tt + 1) & 1][w][e] = bm;
            }
        }
        __syncthreads();
    }

    // den: lanes {m, m+16, m+32, m+48} hold partials for row m
    den += __shfl_xor(den, 16);
    den += __shfl_xor(den, 32);
    if (l < 16) sden[w * 16 + l] = den;
    // D layout (verified R2): out row = quad*4 + reg, channel = nt*16 + (lane&15)
    #pragma unroll
    for (int nt = 0; nt < 4; ++nt)
        #pragma unroll
        for (int r = 0; r < 4; ++r)
            sacc[w * 1024 + (quad * 4 + r) * 64 + nt * 16 + m] = acc[nt][r];
    __syncthreads();
    // epilogue: thread t owns output (row = t>>6, ch = t&63) of this 16x64 tile
    float s = 0.f;
    #pragma unroll
    for (int w2 = 0; w2 < 16; ++w2) s += sacc[w2 * 1024 + t];
    float dden = 0.f;
    const int orow = t >> 6;
    #pragma unroll
    for (int w2 = 0; w2 < 16; ++w2) dden += sden[w2 * 16 + orow];
    out[(size_t)i0 * OUTC + t] = elu1(s / dden);
}

extern "C" void kernel_launch(void* const* d_in, const int* in_sizes, int n_in,
                              void* d_out, int out_size, void* d_ws, size_t ws_size,
                              hipStream_t stream) {
    const float* H  = (const float*)d_in[0];
    const int* adj  = (const int*)d_in[1];
    const float* W  = (const float*)d_in[2];
    const float* a  = (const float*)d_in[3];
    float* out = (float*)d_out;
    char* ws = (char*)d_ws;
    // ws: WhT 512K | f1 16K | f2 16K
    unsigned short* WhT = (unsigned short*)(ws);
    float* f1 = (float*)(ws + (512 << 10));
    float* f2 = (float*)(ws + (528 << 10));
    hipLaunchKernelGGL(k_wh,  dim3(256), dim3(256),  0, stream, H, W, a, WhT, f1, f2);
    hipLaunchKernelGGL(k_att, dim3(256), dim3(1024), 0, stream,
                       adj, (const _Float16*)WhT, f1, f2, out);
}

// Round 8
// 126.918 us; speedup vs baseline: 1.9615x; 1.0048x over previous
//
#include <hip/hip_runtime.h>
#include <math.h>

static constexpr int NN   = 4096;
static constexpr int INC  = 256;
static constexpr int OUTC = 64;

typedef _Float16 half8 __attribute__((ext_vector_type(8)));
typedef float floatx4 __attribute__((ext_vector_type(4)));

__device__ __forceinline__ float lrelu(float x) {
    return fmaxf(x, 0.f) + 0.2f * fminf(x, 0.f);
}
__device__ __forceinline__ float elu1(float x) {
    return x > 0.f ? x : (__expf(x) - 1.f);
}

// K1: Wh = H@W -> fp16 WhT (transposed 64 x 4096); f1 = Wh@a1; f2 = Wh@a2.
// (R5/R7-verified, unchanged.)
__global__ __launch_bounds__(256) void k_wh(const float* __restrict__ H,
                                            const float* __restrict__ W,
                                            const float* __restrict__ a,
                                            unsigned short* __restrict__ WhT,
                                            float* __restrict__ f1,
                                            float* __restrict__ f2) {
    __shared__ __align__(16) float Hl[16 * INC];   // 16 KB
    __shared__ _Float16 Tl[16 * 68];               // 2.2 KB transpose buffer
    const int t = threadIdx.x;
    const int i0 = blockIdx.x * 16;
    {
        const float4* H4 = (const float4*)(H + i0 * INC);
        float4* Hl4 = (float4*)Hl;
        #pragma unroll
        for (int u = 0; u < 4; ++u) Hl4[u * 256 + t] = H4[u * 256 + t];
    }
    __syncthreads();
    const int c = t & 63;
    const int g = t >> 6;
    const float a1c = a[c];
    const float a2c = a[OUTC + c];
    float acc[4] = {0.f, 0.f, 0.f, 0.f};
    const float4* Hl4 = (const float4*)Hl;
    #pragma unroll 4
    for (int k4 = 0; k4 < INC / 4; ++k4) {
        const float w0 = W[(k4 * 4 + 0) * OUTC + c];
        const float w1 = W[(k4 * 4 + 1) * OUTC + c];
        const float w2 = W[(k4 * 4 + 2) * OUTC + c];
        const float w3 = W[(k4 * 4 + 3) * OUTC + c];
        #pragma unroll
        for (int s = 0; s < 4; ++s) {
            const float4 h = Hl4[(g + 4 * s) * (INC / 4) + k4];
            acc[s] = fmaf(h.x, w0, fmaf(h.y, w1, fmaf(h.z, w2, fmaf(h.w, w3, acc[s]))));
        }
    }
    #pragma unroll
    for (int s = 0; s < 4; ++s) {
        const int r = g + 4 * s;
        Tl[r * 68 + c] = (_Float16)acc[s];
        float v1 = acc[s] * a1c;
        float v2 = acc[s] * a2c;
        #pragma unroll
        for (int off = 32; off; off >>= 1) {
            v1 += __shfl_xor(v1, off);
            v2 += __shfl_xor(v2, off);
        }
        if (c == 0) { f1[i0 + r] = v1; f2[i0 + r] = v2; }
    }
    __syncthreads();
    const int c2 = t >> 2;
    const int rs = (t & 3) * 4;
    ushort4 u;
    u.x = *(const unsigned short*)&Tl[(rs + 0) * 68 + c2];
    u.y = *(const unsigned short*)&Tl[(rs + 1) * 68 + c2];
    u.z = *(const unsigned short*)&Tl[(rs + 2) * 68 + c2];
    u.w = *(const unsigned short*)&Tl[(rs + 3) * 68 + c2];
    *(ushort4*)(WhT + c2 * NN + i0 + rs) = u;
}

// K2: fused attention, barrier-free K-loop.
// 256 blocks x 1024 threads (16 waves). Block owns rows i0..i0+15, all 4096 j.
// Wave w owns j-slice [w*256, w*256+256) for ALL 16 rows: it packs its own
// masks (16 coalesced int4 loads + 4 ballots/row; lane keeps row m=l&15's four
// u64 words in registers via select) -> no LDS masks, no mid-kernel barriers,
// continuous adj stream. Then 8 MFMA K-steps over its slice. Two barriers
// total: sf2/smax staging + epilogue reduce.
__global__ __launch_bounds__(1024, 4) void k_att(const int* __restrict__ adj,
                                                 const _Float16* __restrict__ WhT,
                                                 const float* __restrict__ f1,
                                                 const float* __restrict__ f2,
                                                 float* __restrict__ out) {
    __shared__ __align__(16) float sf2[NN];          // 16 KB
    __shared__ __align__(16) float sacc[16 * 1024];  // 64 KB
    __shared__ float sden[16 * 16];
    __shared__ float smax[16];
    const int t = threadIdx.x;
    const int w = t >> 6;          // wave 0..15
    const int l = t & 63;
    const int m = l & 15;          // A row (= output row within tile)
    const int quad = l >> 4;       // k-group
    const int i0 = blockIdx.x * 16;
    const int J0 = w * 256;        // this wave's j-slice

    // stage f2 -> LDS + per-wave max (barrier below covers both)
    {
        const float4 v = ((const float4*)f2)[t];
        ((float4*)sf2)[t] = v;
        float mloc = fmaxf(fmaxf(v.x, v.y), fmaxf(v.z, v.w));
        #pragma unroll
        for (int off = 32; off; off >>= 1) mloc = fmaxf(mloc, __shfl_xor(mloc, off));
        if (l == 0) smax[w] = mloc;
    }

    // wave-private pack: masks for rows 0..15 over j in [J0, J0+256)
    // ballot c of row r: bit i <-> adj[i0+r][J0 + 4*i + c]
    unsigned long long mw0 = 0, mw1 = 0, mw2 = 0, mw3 = 0;  // row m's 4 words
    {
        const int* abase = adj + (size_t)i0 * NN + J0 + l * 4;
        #pragma unroll 4
        for (int r = 0; r < 16; ++r) {
            const int4 av = *(const int4*)(abase + (size_t)r * NN);
            const unsigned long long b0 = __ballot(av.x > 0);
            const unsigned long long b1 = __ballot(av.y > 0);
            const unsigned long long b2 = __ballot(av.z > 0);
            const unsigned long long b3 = __ballot(av.w > 0);
            if (m == r) { mw0 = b0; mw1 = b1; mw2 = b2; mw3 = b3; }
        }
    }
    __syncthreads();

    float maxf2 = smax[0];
    #pragma unroll
    for (int k = 1; k < 16; ++k) maxf2 = fmaxf(maxf2, smax[k]);
    const float f1r = f1[i0 + m];
    const float mrow = lrelu(f1r + maxf2);  // exact per-row softmax max (lrelu monotone)

    float den = 0.f;
    floatx4 acc[4] = {{0.f,0.f,0.f,0.f},{0.f,0.f,0.f,0.f},{0.f,0.f,0.f,0.f},{0.f,0.f,0.f,0.f}};

    #pragma unroll 2
    for (int s = 0; s < 8; ++s) {
        const int j = J0 + s * 32 + quad * 8;
        const unsigned int ub = s * 8 + quad * 2;   // bit index base
        const float4 g0 = *(const float4*)(sf2 + j);
        const float4 g1 = *(const float4*)(sf2 + j + 4);
        half8 af;
        {
            float p;
            p = __expf(lrelu(f1r + g0.x) - mrow); den += p; af[0] = ((mw0 >> ub)       & 1ull) ? (_Float16)p : (_Float16)0.f;
            p = __expf(lrelu(f1r + g0.y) - mrow); den += p; af[1] = ((mw1 >> ub)       & 1ull) ? (_Float16)p : (_Float16)0.f;
            p = __expf(lrelu(f1r + g0.z) - mrow); den += p; af[2] = ((mw2 >> ub)       & 1ull) ? (_Float16)p : (_Float16)0.f;
            p = __expf(lrelu(f1r + g0.w) - mrow); den += p; af[3] = ((mw3 >> ub)       & 1ull) ? (_Float16)p : (_Float16)0.f;
            p = __expf(lrelu(f1r + g1.x) - mrow); den += p; af[4] = ((mw0 >> (ub + 1)) & 1ull) ? (_Float16)p : (_Float16)0.f;
            p = __expf(lrelu(f1r + g1.y) - mrow); den += p; af[5] = ((mw1 >> (ub + 1)) & 1ull) ? (_Float16)p : (_Float16)0.f;
            p = __expf(lrelu(f1r + g1.z) - mrow); den += p; af[6] = ((mw2 >> (ub + 1)) & 1ull) ? (_Float16)p : (_Float16)0.f;
            p = __expf(lrelu(f1r + g1.w) - mrow); den += p; af[7] = ((mw3 >> (ub + 1)) & 1ull) ? (_Float16)p : (_Float16)0.f;
        }
        #pragma unroll
        for (int nt = 0; nt < 4; ++nt) {
            const half8 bf = *(const half8*)(WhT + (size_t)(nt * 16 + m) * NN + j);
            acc[nt] = __builtin_amdgcn_mfma_f32_16x16x32_f16(af, bf, acc[nt], 0, 0, 0);
        }
    }
    // den: lanes {m, m+16, m+32, m+48} hold partials for row m over this slice
    den += __shfl_xor(den, 16);
    den += __shfl_xor(den, 32);
    if (l < 16) sden[w * 16 + l] = den;
    // D layout (verified R2): out row = quad*4 + reg, channel = nt*16 + (lane&15)
    #pragma unroll
    for (int nt = 0; nt < 4; ++nt)
        #pragma unroll
        for (int r = 0; r < 4; ++r)
            sacc[w * 1024 + (quad * 4 + r) * 64 + nt * 16 + m] = acc[nt][r];
    __syncthreads();
    // epilogue: thread t owns output (row = t>>6, ch = t&63) of this 16x64 tile
    float s = 0.f;
    #pragma unroll
    for (int w2 = 0; w2 < 16; ++w2) s += sacc[w2 * 1024 + t];
    float dden = 0.f;
    const int orow = t >> 6;
    #pragma unroll
    for (int w2 = 0; w2 < 16; ++w2) dden += sden[w2 * 16 + orow];
    out[(size_t)i0 * OUTC + t] = elu1(s / dden);
}

extern "C" void kernel_launch(void* const* d_in, const int* in_sizes, int n_in,
                              void* d_out, int out_size, void* d_ws, size_t ws_size,
                              hipStream_t stream) {
    const float* H  = (const float*)d_in[0];
    const int* adj  = (const int*)d_in[1];
    const float* W  = (const float*)d_in[2];
    const float* a  = (const float*)d_in[3];
    float* out = (float*)d_out;
    char* ws = (char*)d_ws;
    // ws: WhT 512K | f1 16K | f2 16K
    unsigned short* WhT = (unsigned short*)(ws);
    float* f1 = (float*)(ws + (512 << 10));
    float* f2 = (float*)(ws + (528 << 10));
    hipLaunchKernelGGL(k_wh,  dim3(256), dim3(256),  0, stream, H, W, a, WhT, f1, f2);
    hipLaunchKernelGGL(k_att, dim3(256), dim3(1024), 0, stream,
                       adj, (const _Float16*)WhT, f1, f2, out);
}

// Round 9
// 123.676 us; speedup vs baseline: 2.0129x; 1.0262x over previous
//
#include <hip/hip_runtime.h>
#include <math.h>

static constexpr int NN   = 4096;
static constexpr int INC  = 256;
static constexpr int OUTC = 64;

typedef _Float16 half8 __attribute__((ext_vector_type(8)));
typedef float floatx4 __attribute__((ext_vector_type(4)));

__device__ __forceinline__ float lrelu(float x) {
    return fmaxf(x, 0.f) + 0.2f * fminf(x, 0.f);
}
__device__ __forceinline__ float elu1(float x) {
    return x > 0.f ? x : (__expf(x) - 1.f);
}

// K_prep: fused independent front-end work, one launch.
//  - blocks 0..255   : Wh = H@W -> fp16 WhT (transposed), f1 = Wh@a1, f2 = Wh@a2
//                      (W read straight from L2, coalesced; LDS only 18.5 KB so
//                       pack blocks co-resident on the same CUs keep HBM saturated)
//  - blocks 256..2303: pack adj (64 MB) -> 2 MB bitmask, dense streaming read.
__global__ __launch_bounds__(256) void k_prep(const int* __restrict__ adj,
                                              unsigned int* __restrict__ bits,
                                              const float* __restrict__ H,
                                              const float* __restrict__ W,
                                              const float* __restrict__ a,
                                              unsigned short* __restrict__ WhT,
                                              float* __restrict__ f1,
                                              float* __restrict__ f2) {
    const int t = threadIdx.x;
    if (blockIdx.x >= 256) {
        // ---- pack branch ----
        const int tau = (blockIdx.x - 256) * 256 + t;        // 0..524287
        const int4* src = (const int4*)adj + (size_t)tau * 8;
        unsigned int o = 0;
        #pragma unroll
        for (int u = 0; u < 8; ++u) {
            const int4 v = src[u];
            const unsigned int nib = (unsigned int)(v.x > 0)
                                   | ((unsigned int)(v.y > 0) << 1)
                                   | ((unsigned int)(v.z > 0) << 2)
                                   | ((unsigned int)(v.w > 0) << 3);
            o |= nib << (4 * u);
        }
        bits[tau] = o;
        return;
    }
    // ---- wh branch ----
    __shared__ __align__(16) float Hl[16 * INC];   // 16 KB
    __shared__ _Float16 Tl[16 * 68];               // 2.2 KB transpose buffer
    const int i0 = blockIdx.x * 16;
    {
        const float4* H4 = (const float4*)(H + i0 * INC);
        float4* Hl4 = (float4*)Hl;
        #pragma unroll
        for (int u = 0; u < 4; ++u) Hl4[u * 256 + t] = H4[u * 256 + t];
    }
    __syncthreads();
    const int c = t & 63;       // channel (lane)
    const int g = t >> 6;       // wave -> row group
    const float a1c = a[c];
    const float a2c = a[OUTC + c];
    float acc[4] = {0.f, 0.f, 0.f, 0.f};
    const float4* Hl4 = (const float4*)Hl;
    #pragma unroll 4
    for (int k4 = 0; k4 < INC / 4; ++k4) {
        const float w0 = W[(k4 * 4 + 0) * OUTC + c];   // coalesced, L2-hit
        const float w1 = W[(k4 * 4 + 1) * OUTC + c];
        const float w2 = W[(k4 * 4 + 2) * OUTC + c];
        const float w3 = W[(k4 * 4 + 3) * OUTC + c];
        #pragma unroll
        for (int s = 0; s < 4; ++s) {
            const float4 h = Hl4[(g + 4 * s) * (INC / 4) + k4];
            acc[s] = fmaf(h.x, w0, fmaf(h.y, w1, fmaf(h.z, w2, fmaf(h.w, w3, acc[s]))));
        }
    }
    #pragma unroll
    for (int s = 0; s < 4; ++s) {
        const int r = g + 4 * s;
        Tl[r * 68 + c] = (_Float16)acc[s];
        float v1 = acc[s] * a1c;
        float v2 = acc[s] * a2c;
        #pragma unroll
        for (int off = 32; off; off >>= 1) {
            v1 += __shfl_xor(v1, off);
            v2 += __shfl_xor(v2, off);
        }
        if (c == 0) { f1[i0 + r] = v1; f2[i0 + r] = v2; }
    }
    __syncthreads();
    const int c2 = t >> 2;
    const int rs = (t & 3) * 4;
    ushort4 u;
    u.x = *(const unsigned short*)&Tl[(rs + 0) * 68 + c2];
    u.y = *(const unsigned short*)&Tl[(rs + 1) * 68 + c2];
    u.z = *(const unsigned short*)&Tl[(rs + 2) * 68 + c2];
    u.w = *(const unsigned short*)&Tl[(rs + 3) * 68 + c2];
    *(ushort4*)(WhT + c2 * NN + i0 + rs) = u;
}

// K_att: fused attention, 16 rows x all 4096 j per block, 16 waves.
// adj mask from the 2 MB bitmask (L2-resident, 1 byte per lane-iter).
__global__ __launch_bounds__(1024, 4) void k_att(const unsigned char* __restrict__ bits,
                                                 const _Float16* __restrict__ WhT,
                                                 const float* __restrict__ f1,
                                                 const float* __restrict__ f2,
                                                 float* __restrict__ out) {
    __shared__ __align__(16) float sf2[NN];         // 16 KB
    __shared__ __align__(16) float sacc[16 * 1024]; // 64 KB
    __shared__ float sden[16 * 16];
    __shared__ float smax[16];
    const int t = threadIdx.x;
    const int w = t >> 6;          // wave 0..15
    const int l = t & 63;
    const int m = l & 15;          // A row (= output row within tile)
    const int quad = l >> 4;       // k-group
    const int i0 = blockIdx.x * 16;

    // pre-pass: f2 -> LDS, block max
    {
        const float4 v = ((const float4*)f2)[t];
        ((float4*)sf2)[t] = v;
        float mloc = fmaxf(fmaxf(v.x, v.y), fmaxf(v.z, v.w));
        #pragma unroll
        for (int off = 32; off; off >>= 1) mloc = fmaxf(mloc, __shfl_xor(mloc, off));
        if (l == 0) smax[w] = mloc;
    }
    __syncthreads();
    float maxf2 = smax[0];
    #pragma unroll
    for (int k = 1; k < 16; ++k) maxf2 = fmaxf(maxf2, smax[k]);

    const float f1r = f1[i0 + m];
    const float mrow = lrelu(f1r + maxf2);  // exact per-row softmax max (lrelu monotone)
    float den = 0.f;
    floatx4 acc[4] = {{0.f,0.f,0.f,0.f},{0.f,0.f,0.f,0.f},{0.f,0.f,0.f,0.f},{0.f,0.f,0.f,0.f}};
    const int jbase = w * 32 + quad * 8;
    const unsigned char* brow = bits + (size_t)(i0 + m) * (NN / 8) + (jbase >> 3);
    unsigned int m8[8];
    #pragma unroll
    for (int it = 0; it < 8; ++it) m8[it] = brow[it * 64];

    #pragma unroll 2
    for (int it = 0; it < 8; ++it) {
        const int j = jbase + it * 512;
        const unsigned int mb = m8[it];
        const float4 g0 = *(const float4*)(sf2 + j);
        const float4 g1 = *(const float4*)(sf2 + j + 4);
        half8 af;
        {
            float p;
            p = __expf(lrelu(f1r + g0.x) - mrow); den += p; af[0] = (mb & 1u)   ? (_Float16)p : (_Float16)0.f;
            p = __expf(lrelu(f1r + g0.y) - mrow); den += p; af[1] = (mb & 2u)   ? (_Float16)p : (_Float16)0.f;
            p = __expf(lrelu(f1r + g0.z) - mrow); den += p; af[2] = (mb & 4u)   ? (_Float16)p : (_Float16)0.f;
            p = __expf(lrelu(f1r + g0.w) - mrow); den += p; af[3] = (mb & 8u)   ? (_Float16)p : (_Float16)0.f;
            p = __expf(lrelu(f1r + g1.x) - mrow); den += p; af[4] = (mb & 16u)  ? (_Float16)p : (_Float16)0.f;
            p = __expf(lrelu(f1r + g1.y) - mrow); den += p; af[5] = (mb & 32u)  ? (_Float16)p : (_Float16)0.f;
            p = __expf(lrelu(f1r + g1.z) - mrow); den += p; af[6] = (mb & 64u)  ? (_Float16)p : (_Float16)0.f;
            p = __expf(lrelu(f1r + g1.w) - mrow); den += p; af[7] = (mb & 128u) ? (_Float16)p : (_Float16)0.f;
        }
        #pragma unroll
        for (int nt = 0; nt < 4; ++nt) {
            const half8 bf = *(const half8*)(WhT + (size_t)(nt * 16 + m) * NN + j);
            acc[nt] = __builtin_amdgcn_mfma_f32_16x16x32_f16(af, bf, acc[nt], 0, 0, 0);
        }
    }
    den += __shfl_xor(den, 16);
    den += __shfl_xor(den, 32);
    if (l < 16) sden[w * 16 + l] = den;
    // D layout (verified R2): out row = quad*4 + reg, channel = nt*16 + (lane&15)
    #pragma unroll
    for (int nt = 0; nt < 4; ++nt)
        #pragma unroll
        for (int r = 0; r < 4; ++r)
            sacc[w * 1024 + (quad * 4 + r) * 64 + nt * 16 + m] = acc[nt][r];
    __syncthreads();
    float s = 0.f;
    #pragma unroll
    for (int w2 = 0; w2 < 16; ++w2) s += sacc[w2 * 1024 + t];
    float dden = 0.f;
    const int row = t >> 6;
    #pragma unroll
    for (int w2 = 0; w2 < 16; ++w2) dden += sden[w2 * 16 + row];
    out[(size_t)i0 * OUTC + t] = elu1(s / dden);
}

extern "C" void kernel_launch(void* const* d_in, const int* in_sizes, int n_in,
                              void* d_out, int out_size, void* d_ws, size_t ws_size,
                              hipStream_t stream) {
    const float* H  = (const float*)d_in[0];
    const int* adj  = (const int*)d_in[1];
    const float* W  = (const float*)d_in[2];
    const float* a  = (const float*)d_in[3];
    float* out = (float*)d_out;
    char* ws = (char*)d_ws;
    // ws: WhT 512K | f1 16K | f2 16K | bits 2M @ 1M
    unsigned short* WhT = (unsigned short*)(ws);
    float* f1 = (float*)(ws + (512 << 10));
    float* f2 = (float*)(ws + (528 << 10));
    unsigned int* bits = (unsigned int*)(ws + (1 << 20));
    hipLaunchKernelGGL(k_prep, dim3(2304), dim3(256), 0, stream,
                       adj, bits, H, W, a, WhT, f1, f2);
    hipLaunchKernelGGL(k_att,  dim3(256),  dim3(1024), 0, stream,
                       (const unsigned char*)bits, (const _Float16*)WhT, f1, f2, out);
}